// Round 1
// baseline (54.658 us; speedup 1.0000x reference)
//
#include <hip/hip_runtime.h>
#include <math.h>

#define NUM_BINS 15
#define FL_EPS 1e-20f

// Stage 1: one wave (64 lanes) per row. Row (C=1000 floats) is loaded once
// into registers as float4s; max and sum(exp) computed via shfl butterflies.
// Each wave grid-strides over rows, accumulating its local loss sum; block
// reduces 4 wave-partials to one float in d_ws[blockIdx].
__global__ __launch_bounds__(256) void adafocal_stage1(
    const float* __restrict__ input, const int* __restrict__ target,
    const float* __restrict__ gammas, float* __restrict__ partial,
    int N, int C)
{
    const int lane        = threadIdx.x & 63;
    const int waveInBlock = threadIdx.x >> 6;
    const int globalWave  = blockIdx.x * 4 + waveInBlock;
    const int totalWaves  = gridDim.x * 4;
    const int nvec = C >> 2;      // 250 for C=1000
    const int tail = C & 3;       // 0 for C=1000

    float acc = 0.0f;

    for (int row = globalWave; row < N; row += totalWaves) {
        const float* rowp = input + (size_t)row * (size_t)C;

        // ---- pass: load row into registers, lane-local max ----
        float4 v[4];
        float mx = -INFINITY;
        #pragma unroll
        for (int it = 0; it < 4; ++it) {
            int j = lane + it * 64;
            if (j < nvec) {
                float4 f = reinterpret_cast<const float4*>(rowp)[j];
                v[it] = f;
                mx = fmaxf(fmaxf(mx, fmaxf(f.x, f.y)), fmaxf(f.z, f.w));
            }
        }
        float tx = -INFINITY;
        if (lane < tail) { tx = rowp[(nvec << 2) + lane]; mx = fmaxf(mx, tx); }

        // wave-reduce max (64 lanes)
        #pragma unroll
        for (int off = 32; off >= 1; off >>= 1)
            mx = fmaxf(mx, __shfl_xor(mx, off, 64));

        // ---- sum of exp(x - max) from registers ----
        float s = 0.0f;
        #pragma unroll
        for (int it = 0; it < 4; ++it) {
            int j = lane + it * 64;
            if (j < nvec) {
                float4 f = v[it];
                s += __expf(f.x - mx) + __expf(f.y - mx)
                   + __expf(f.z - mx) + __expf(f.w - mx);
            }
        }
        if (lane < tail) s += __expf(tx - mx);

        #pragma unroll
        for (int off = 32; off >= 1; off >>= 1)
            s += __shfl_xor(s, off, 64);

        // ---- scalar epilogue on lane 0 ----
        if (lane == 0) {
            float logZ  = mx + __logf(s);
            int   t     = target[row];
            float logpt = rowp[t] - logZ;   // L1-resident re-read of 1 element
            float pt    = __expf(logpt);
            int bin = (int)(pt * (float)NUM_BINS);
            bin = min(max(bin, 0), NUM_BINS - 1);
            float g  = gammas[bin];
            float gs = (g > 0.0f) ? 1.0f : ((g < 0.0f) ? -1.0f : 0.0f);
            float gm = fabsf(g);
            float base = 1.0f - gs * pt + FL_EPS;
            acc += -powf(base, gm) * logpt;
        }
    }

    __shared__ float lds[4];
    if (lane == 0) lds[waveInBlock] = acc;
    __syncthreads();
    if (threadIdx.x == 0)
        partial[blockIdx.x] = lds[0] + lds[1] + lds[2] + lds[3];
}

// Stage 2: one block reduces the 2048 block-partials deterministically.
__global__ __launch_bounds__(256) void adafocal_stage2(
    const float* __restrict__ partial, int n, float* __restrict__ out)
{
    float s = 0.0f;
    for (int i = threadIdx.x; i < n; i += 256) s += partial[i];
    #pragma unroll
    for (int off = 32; off >= 1; off >>= 1)
        s += __shfl_xor(s, off, 64);
    __shared__ float lds[4];
    if ((threadIdx.x & 63) == 0) lds[threadIdx.x >> 6] = s;
    __syncthreads();
    if (threadIdx.x == 0) out[0] = lds[0] + lds[1] + lds[2] + lds[3];
}

extern "C" void kernel_launch(void* const* d_in, const int* in_sizes, int n_in,
                              void* d_out, int out_size, void* d_ws, size_t ws_size,
                              hipStream_t stream) {
    const float* input  = (const float*)d_in[0];
    const int*   target = (const int*)d_in[1];   // harness passes integer inputs as int32
    const float* gammas = (const float*)d_in[2];
    float* out = (float*)d_out;

    const int N = in_sizes[1];             // 65536 rows
    const int C = in_sizes[0] / N;         // 1000 classes

    float* partial = (float*)d_ws;         // 2048 floats = 8 KB scratch
    const int BLOCKS = 2048;               // 8 blocks/CU on 256 CUs

    adafocal_stage1<<<BLOCKS, 256, 0, stream>>>(input, target, gammas, partial, N, C);
    adafocal_stage2<<<1, 256, 0, stream>>>(partial, BLOCKS, out);
}